// Round 14
// baseline (1991.505 us; speedup 1.0000x reference)
//
#include <hip/hip_runtime.h>
#include <hip/hip_bf16.h>
#include <stdint.h>

#define B_    64
#define T_    512
#define NIN_  64
#define N_    1024
#define NOUT_ 32

// persistent-scan decomposition (R2/R11/R12/R13 geometry, verbatim)
#define NISL  16            // islands (independent batch groups)
#define BPI   16            // blocks per island (N-slices)
#define MB    4             // batches per island  = B_/NISL
#define COLS  64            // output cols per block = N_/BPI
#define NT    4             // 16-wide N tiles per block
#define KW    256           // K range per wave = N_/4
#define KT    8             // 32-wide K steps per wave

// mailbox matrix: mail[isl][consumer_slice][producer_wid 0..63] = 64KB total.
// Consumer block (isl,c) polls its PRIVATE 256B (4 lines); producer WAVE wid
// posts its own step counter to the 16 consumer slots at column wid.
#define MAIL_WORDS (NISL * BPI * 64)            // 16384 words = 65536 B

typedef float f32x4 __attribute__((ext_vector_type(4)));
typedef short s16x8 __attribute__((ext_vector_type(8)));

__device__ __forceinline__ unsigned short f2bf(float f) {
  union { float f; unsigned u; } v; v.f = f;
  unsigned r = v.u + 0x7FFFu + ((v.u >> 16) & 1u);   // RNE, no NaN in data
  return (unsigned short)(r >> 16);
}

__device__ __forceinline__ s16x8 cvt8(float4 a, float4 b) {
  s16x8 f;
  f[0] = (short)f2bf(a.x); f[1] = (short)f2bf(a.y);
  f[2] = (short)f2bf(a.z); f[3] = (short)f2bf(a.w);
  f[4] = (short)f2bf(b.x); f[5] = (short)f2bf(b.y);
  f[6] = (short)f2bf(b.z); f[7] = (short)f2bf(b.w);
  return f;
}

// Vectorized exchange reads — EXACT R7/R13-proven pattern:
// global_load_dwordx4 sc0 sc1 (coherence-point fresh) + vmcnt(0) + SBAR(0).
#define LD16S(dst, base, OFF) \
  asm volatile("global_load_dwordx4 %0, %1, off offset:" #OFF " sc0 sc1" \
               : "=v"(dst) : "v"(base) : "memory")
#define LDALLS() do { \
  LD16S(afr[0], bp, 0);   LD16S(afr[1], bp, 64);  \
  LD16S(afr[2], bp, 128); LD16S(afr[3], bp, 192); \
  LD16S(afr[4], bp, 256); LD16S(afr[5], bp, 320); \
  LD16S(afr[6], bp, 384); LD16S(afr[7], bp, 448); } while (0)

// ---------------------------------------------------------------------------
// Persistent scan — R13 with two serial-path stall removals:
//  1. X/R stores moved to the step TAIL (after the post, R7 placement): the
//     post-LDALLS vmcnt(0) now waits ONLY the 8 exchange loads, not HBM
//     store acks (R13's hidden ~0.2us/step stall).
//  2. B_drain barrier removed: per-wave publish -> per-wave vmcnt(0) drain
//     (own stores only, R7-proven producer pattern) -> per-wave post into
//     mail[isl][consumer][producer_wid]. One barrier per step (B_part).
// Ordering: data-ack-before-post preserved PER WAVE; poll(t) certifies all
// 64 island waves finished step t-1 (their part[]-reads and buffer-reads),
// gating part[] reuse and exchange overwrite exactly as before.
// All sync primitives: compiler relaxed agent atomics (proven-live class).
// ---------------------------------------------------------------------------
__global__ __launch_bounds__(256, 1) void rnn_scan(
    const float* __restrict__ U, const float* __restrict__ X0,
    const float* __restrict__ SN, const float* __restrict__ RN,
    const float* __restrict__ Wi, const float* __restrict__ Bi,
    const float* __restrict__ Wr,
    float* __restrict__ X, float* __restrict__ R,
    unsigned* __restrict__ mail, unsigned* __restrict__ ex)
{
  const int bid   = blockIdx.x;
  const int isl   = bid / BPI, slice = bid % BPI;
  const int tid   = threadIdx.x;
  const int wave  = tid >> 6, lane = tid & 63;
  const int l15   = lane & 15, koct = lane >> 4;
  const int colbase = slice * COLS;
  const int wid   = slice * 4 + wave;              // island-wave id 0..63

  // --- resident B fragments of W_rec slice: B[k][n] = W_rec[col n][k] ---
  s16x8 bfrag[KT][NT];
#pragma unroll
  for (int kt = 0; kt < KT; ++kt) {
    const int k0 = wave * KW + kt * 32 + koct * 8;
#pragma unroll
    for (int nt = 0; nt < NT; ++nt) {
      const float4* q = (const float4*)(Wr + (size_t)(colbase + nt * 16 + l15) * N_ + k0);
      bfrag[kt][nt] = cvt8(q[0], q[1]);
    }
  }
  // --- W_in fragments: input term split across waves 0,1 (K=64 = 2x32) ---
  s16x8 wifrag[NT];
  if (wave < 2) {
#pragma unroll
    for (int nt = 0; nt < NT; ++nt) {
      const float4* q = (const float4*)(Wi + (size_t)(colbase + nt * 16 + l15) * NIN_ + wave * 32 + koct * 8);
      wifrag[nt] = cvt8(q[0], q[1]);
    }
  }

  // thread (wave, lane) owns state element (batch = wave, col = lane)
  const int cc   = lane;
  const int bloc = wave;
  const int bg   = isl * MB + bloc;                 // global batch
  const int nn   = colbase + cc;                    // global col
  const int abatch = isl * MB + (l15 & 3);          // A-row batch (rows dup 4x)

  float x = X0[nn];
  const float bin = Bi[nn];
  const float r0 = fmaxf(tanhf(x), 0.f);

  __shared__ float part[4][COLS][MB];               // [wave][col][batch^swz]

  // consumer-private poll lines (4 x 64B); producer post column at wid
  const unsigned* const myline = mail + (size_t)(isl * BPI + slice) * 64;

  // publish r_0 (8B wt atomics) -> per-wave drain -> per-wave post slot=1
  {
    unsigned short h = f2bf(r0);
    unsigned other = __shfl_xor((unsigned)h, 1);
    unsigned vv  = (unsigned)h | (other << 16);        // cols (nn&~1, nn|1)
    unsigned vv2 = __shfl_xor(vv, 2);                  // cols (+2, +3)
    if ((lane & 3) == 0) {
      uint64_t q8 = (uint64_t)vv | ((uint64_t)vv2 << 32);
      __hip_atomic_store((uint64_t*)(ex + (size_t)bg * (N_ / 2) + (nn >> 1)), q8,
                         __ATOMIC_RELAXED, __HIP_MEMORY_SCOPE_AGENT);
    }
  }
  asm volatile("s_waitcnt vmcnt(0)" ::: "memory");   // own publish drained
  if (lane < BPI)
    __hip_atomic_store(mail + (size_t)(isl * BPI + lane) * 64 + wid, 1u,
                       __ATOMIC_RELAXED, __HIP_MEMORY_SCOPE_AGENT);

  for (int t = 0; t < T_; ++t) {
    const int par = t & 1;
    const size_t row = (size_t)bg * T_ + t;

    // top loads: issued before the wait, consumed after MFMA/update; their
    // acks retire during the poll (off the drain path)
    const float snv = SN[row * N_ + nn];
    const float rnv = RN[row * N_ + nn];
    float4 uq0, uq1;
    if (wave < 2) {
      const float4* q = (const float4*)(U + ((size_t)(isl * MB + (l15 & 3)) * T_ + t) * NIN_
                                          + wave * 32 + koct * 8);
      uq0 = q[0]; uq1 = q[1];
    }

    // per-wave poll: lane L checks producer-wave slot L on OUR private lines
    {
      const unsigned need = (unsigned)(t + 1);
      for (;;) {
        unsigned fv = __hip_atomic_load(myline + lane, __ATOMIC_RELAXED,
                                        __HIP_MEMORY_SCOPE_AGENT);
        if (__all((int)(fv >= need))) break;
        __builtin_amdgcn_s_sleep(1);
      }
    }

    // A fragments: vectorized coherence-point loads. ONLY these are
    // outstanding here (X/R stores are at the step tail; top loads retired
    // under the poll) -> vmcnt(0) == exchange-load RT, nothing else.
    const unsigned* bp = ex + (size_t)par * (B_ * (N_ / 2))
                            + (size_t)abatch * (N_ / 2)
                            + ((wave * KW + koct * 8) >> 1);
    s16x8 afr[KT];
    LDALLS();
    asm volatile("s_waitcnt vmcnt(0)" ::: "memory");
    __builtin_amdgcn_sched_barrier(0);   // rule #18: keep MFMA below the wait

    f32x4 acc[NT];
#pragma unroll
    for (int nt = 0; nt < NT; ++nt) acc[nt] = f32x4{0.f, 0.f, 0.f, 0.f};
#pragma unroll
    for (int kt = 0; kt < KT; ++kt)
#pragma unroll
      for (int nt = 0; nt < NT; ++nt)
        acc[nt] = __builtin_amdgcn_mfma_f32_16x16x32_bf16(afr[kt], bfrag[kt][nt], acc[nt], 0, 0, 0);
    if (wave < 2) {
      s16x8 ua = cvt8(uq0, uq1);
#pragma unroll
      for (int nt = 0; nt < NT; ++nt)
        acc[nt] = __builtin_amdgcn_mfma_f32_16x16x32_bf16(ua, wifrag[nt], acc[nt], 0, 0, 0);
    }

    // cross-wave K-partials; XOR-swizzled slot layout (R4-proven, conflict-0)
    if (lane < 16) {
#pragma unroll
      for (int nt = 0; nt < NT; ++nt) {
        const int s = (nt * 2 + (lane >> 3)) & 3;
        f32x4 a = acc[nt];
        if (s & 1) a = f32x4{a[1], a[0], a[3], a[2]};
        if (s & 2) a = f32x4{a[2], a[3], a[0], a[1]};
        *(f32x4*)&part[wave][nt * 16 + lane][0] = a;   // slot j holds acc[j^s]
      }
    }
    __syncthreads();                                   // B_part (only barrier)
    const int sr = (cc >> 3) & 3;
    const float mat = part[0][cc][bloc ^ sr] + part[1][cc][bloc ^ sr] +
                      part[2][cc][bloc ^ sr] + part[3][cc][bloc ^ sr];
    const float xn = x + 0.1f * (-x + mat + bin + snv);
    const float rv = fmaxf(tanhf(xn), 0.f) + rnv;
    x = xn;

    // publish r_{t+1} (8B wt atomics) -> per-wave drain -> per-wave post.
    // No block barrier: each wave posts as soon as ITS data is globally
    // visible; poll-side needs all 64 wave slots anyway.
    {
      unsigned short h = f2bf(rv);
      unsigned other = __shfl_xor((unsigned)h, 1);
      unsigned vv  = (unsigned)h | (other << 16);
      unsigned vv2 = __shfl_xor(vv, 2);
      if ((lane & 3) == 0) {
        uint64_t q8 = (uint64_t)vv | ((uint64_t)vv2 << 32);
        __hip_atomic_store((uint64_t*)(ex + (size_t)(par ^ 1) * (B_ * (N_ / 2)) +
                                       (size_t)bg * (N_ / 2) + (nn >> 1)), q8,
                           __ATOMIC_RELAXED, __HIP_MEMORY_SCOPE_AGENT);
      }
    }
    asm volatile("s_waitcnt vmcnt(0)" ::: "memory");   // own publish only
    if (lane < BPI)
      __hip_atomic_store(mail + (size_t)(isl * BPI + lane) * 64 + wid,
                         (unsigned)(t + 2),
                         __ATOMIC_RELAXED, __HIP_MEMORY_SCOPE_AGENT);

    // tail: X/R stores strictly after the post — their HBM acks retire
    // during the next step's poll, never on a vmcnt(0) drain
    X[row * N_ + nn] = xn;
    R[row * N_ + nn] = rv;
  }
}

// ---------------------------------------------------------------------------
// Z = R @ W_out^T + b_out + output_noise.  W_out register-resident; R rows
// double-buffered in LDS; one barrier per row; 512 blocks (R6/R7/R11-proven).
// ---------------------------------------------------------------------------
#define TCH 64
__global__ __launch_bounds__(256, 2) void rnn_zout(
    const float* __restrict__ Rm, const float* __restrict__ ON,
    const float* __restrict__ Wo, const float* __restrict__ Bo,
    float* __restrict__ Z)
{
  const int bid = blockIdx.x;
  const int b = bid >> 3, tq = bid & 7;
  const int tid = threadIdx.x;
  const int o = tid & 31, kc = tid >> 5;

  float4 wv[32];
  const float4* wp = (const float4*)(Wo + (size_t)o * N_ + kc * 128);
#pragma unroll
  for (int i = 0; i < 32; ++i) wv[i] = wp[i];
  const float bo = Bo[o];

  __shared__ float Rl[2][N_];
  __shared__ float zred[2][8][32];

  const int t0 = tq * TCH;
  ((float4*)Rl[0])[tid] = ((const float4*)(Rm + ((size_t)b * T_ + t0) * N_))[tid];
  __syncthreads();

  for (int i = 0; i < TCH; ++i) {
    const int cur = i & 1;
    const size_t row = (size_t)b * T_ + t0 + i;
    float4 nx;
    if (i + 1 < TCH)
      nx = ((const float4*)(Rm + (row + 1) * N_))[tid];
    float a0 = 0.f;
#pragma unroll
    for (int j = 0; j < 32; ++j) {
      const float* rp = &Rl[cur][kc * 128 + j * 4];
      a0 += wv[j].x * rp[0] + wv[j].y * rp[1] + wv[j].z * rp[2] + wv[j].w * rp[3];
    }
    if (i + 1 < TCH)
      ((float4*)Rl[cur ^ 1])[tid] = nx;
    zred[cur][kc][o] = a0;
    __syncthreads();
    if (tid < 32) {
      float z = bo;
#pragma unroll
      for (int k = 0; k < 8; ++k) z += zred[cur][k][tid];
      Z[row * NOUT_ + tid] = z + ON[row * NOUT_ + tid];
    }
    // reduce(i) reads zred[cur] after barrier(i); the next write to the same
    // zred/Rl buffer happens only after barrier(i+1) gates it. Race-free.
  }
}

extern "C" void kernel_launch(void* const* d_in, const int* in_sizes, int n_in,
                              void* d_out, int out_size, void* d_ws, size_t ws_size,
                              hipStream_t stream) {
  const float* U  = (const float*)d_in[0];
  const float* X0 = (const float*)d_in[1];
  const float* SN = (const float*)d_in[2];
  const float* RN = (const float*)d_in[3];
  const float* ON = (const float*)d_in[4];
  const float* Wi = (const float*)d_in[5];
  const float* Bi = (const float*)d_in[6];
  const float* Wr = (const float*)d_in[7];
  const float* Wo = (const float*)d_in[8];
  const float* Bo = (const float*)d_in[9];

  float* X = (float*)d_out;
  float* R = X + (size_t)B_ * T_ * N_;
  float* Z = R + (size_t)B_ * T_ * N_;

  unsigned* mail = (unsigned*)d_ws;                        // [NISL][16][64]
  unsigned* ex   = (unsigned*)((char*)d_ws + 65536);       // [2][B_][N_/2] bf16x2

  // zero mailboxes every call (graph-capture-safe; 0 < first need of 1)
  hipMemsetAsync(mail, 0, MAIL_WORDS * sizeof(unsigned), stream);

  hipLaunchKernelGGL(rnn_scan, dim3(NISL * BPI), dim3(256), 0, stream,
                     U, X0, SN, RN, Wi, Bi, Wr, X, R, mail, ex);
  hipLaunchKernelGGL(rnn_zout, dim3(B_ * (T_ / TCH)), dim3(256), 0, stream,
                     R, ON, Wo, Bo, Z);
}

// Round 15
// 1489.643 us; speedup vs baseline: 1.3369x; 1.3369x over previous
//
#include <hip/hip_runtime.h>
#include <hip/hip_bf16.h>
#include <stdint.h>

#define B_    64
#define T_    512
#define NIN_  64
#define N_    1024
#define NOUT_ 32

// persistent-scan decomposition (R2/R11/R12/R13 geometry, verbatim)
#define NISL  16            // islands (independent batch groups)
#define BPI   16            // blocks per island (N-slices)
#define MB    4             // batches per island  = B_/NISL
#define COLS  64            // output cols per block = N_/BPI
#define NT    4             // 16-wide N tiles per block
#define KW    256           // K range per wave = N_/4
#define KT    8             // 32-wide K steps per wave

// mailbox matrix: mail[isl][consumer_slice][producer_slice] (16KB total) —
// R12/R13-proven: consumer-private 64B line, block-granular posts.
#define MAIL_WORDS (NISL * BPI * BPI)

typedef float f32x4 __attribute__((ext_vector_type(4)));
typedef short s16x8 __attribute__((ext_vector_type(8)));

__device__ __forceinline__ unsigned short f2bf(float f) {
  union { float f; unsigned u; } v; v.f = f;
  unsigned r = v.u + 0x7FFFu + ((v.u >> 16) & 1u);   // RNE, no NaN in data
  return (unsigned short)(r >> 16);
}

__device__ __forceinline__ s16x8 cvt8(float4 a, float4 b) {
  s16x8 f;
  f[0] = (short)f2bf(a.x); f[1] = (short)f2bf(a.y);
  f[2] = (short)f2bf(a.z); f[3] = (short)f2bf(a.w);
  f[4] = (short)f2bf(b.x); f[5] = (short)f2bf(b.y);
  f[6] = (short)f2bf(b.z); f[7] = (short)f2bf(b.w);
  return f;
}

// Vectorized exchange reads — EXACT R7/R13-proven pattern:
// global_load_dwordx4 sc0 sc1 (coherence-point fresh) + vmcnt(0) + SBAR(0).
#define LD16S(dst, base, OFF) \
  asm volatile("global_load_dwordx4 %0, %1, off offset:" #OFF " sc0 sc1" \
               : "=v"(dst) : "v"(base) : "memory")
#define LDALLS() do { \
  LD16S(afr[0], bp, 0);   LD16S(afr[1], bp, 64);  \
  LD16S(afr[2], bp, 128); LD16S(afr[3], bp, 192); \
  LD16S(afr[4], bp, 256); LD16S(afr[5], bp, 320); \
  LD16S(afr[6], bp, 384); LD16S(afr[7], bp, 448); } while (0)

// ---------------------------------------------------------------------------
// Persistent scan — R13's protocol (best measured: 1452us scan) with ALL
// auxiliary VMEM moved to the step TAIL (after B_drain + post):
//   * X/R stores of the current step   (R14-validated placement, harmless)
//   * SN/RN/U prefetches FOR t+1       (R7-proven 1-deep pattern)
// Effect: at the post-LDALLS vmcnt(0), the only young VMEM is the 8 exchange
// loads; tail ops are ~1us old (covered by post+poll) and retire free. R13's
// hidden stall (drain waiting fresh X/R HBM acks) is gone.
// Poll/post/barriers: R12/R13-proven (private 64B line, block posts, 2 bars).
// ---------------------------------------------------------------------------
__global__ __launch_bounds__(256, 1) void rnn_scan(
    const float* __restrict__ U, const float* __restrict__ X0,
    const float* __restrict__ SN, const float* __restrict__ RN,
    const float* __restrict__ Wi, const float* __restrict__ Bi,
    const float* __restrict__ Wr,
    float* __restrict__ X, float* __restrict__ R,
    unsigned* __restrict__ mail, unsigned* __restrict__ ex)
{
  const int bid   = blockIdx.x;
  const int isl   = bid / BPI, slice = bid % BPI;
  const int tid   = threadIdx.x;
  const int wave  = tid >> 6, lane = tid & 63;
  const int l15   = lane & 15, koct = lane >> 4;
  const int colbase = slice * COLS;

  // --- resident B fragments of W_rec slice: B[k][n] = W_rec[col n][k] ---
  s16x8 bfrag[KT][NT];
#pragma unroll
  for (int kt = 0; kt < KT; ++kt) {
    const int k0 = wave * KW + kt * 32 + koct * 8;
#pragma unroll
    for (int nt = 0; nt < NT; ++nt) {
      const float4* q = (const float4*)(Wr + (size_t)(colbase + nt * 16 + l15) * N_ + k0);
      bfrag[kt][nt] = cvt8(q[0], q[1]);
    }
  }
  // --- W_in fragments: input term split across waves 0,1 (K=64 = 2x32) ---
  s16x8 wifrag[NT];
  if (wave < 2) {
#pragma unroll
    for (int nt = 0; nt < NT; ++nt) {
      const float4* q = (const float4*)(Wi + (size_t)(colbase + nt * 16 + l15) * NIN_ + wave * 32 + koct * 8);
      wifrag[nt] = cvt8(q[0], q[1]);
    }
  }

  // thread (wave, lane) owns state element (batch = wave, col = lane)
  const int cc   = lane;
  const int bloc = wave;
  const int bg   = isl * MB + bloc;                 // global batch
  const int nn   = colbase + cc;                    // global col
  const int abatch = isl * MB + (l15 & 3);          // A-row batch (rows dup 4x)

  float x = X0[nn];
  const float bin = Bi[nn];
  const float r0 = fmaxf(tanhf(x), 0.f);

  const float* SNp = SN + (size_t)bg * T_ * N_ + nn;
  const float* RNp = RN + (size_t)bg * T_ * N_ + nn;
  float*       Xp  = X  + (size_t)bg * T_ * N_ + nn;
  float*       Rp  = R  + (size_t)bg * T_ * N_ + nn;
  const float* Up  = U  + (size_t)(isl * MB + (l15 & 3)) * T_ * NIN_ + wave * 32 + koct * 8;

  __shared__ float part[4][COLS][MB];               // [wave][col][batch^swz]

  // consumer-private poll line; producer post column (R12/R13-proven)
  const unsigned* const myline = mail + (isl * BPI + slice) * BPI;  // 64B line
  unsigned* const postcol      = mail + isl * BPI * BPI + slice;    // +c*16

  // publish r_0 into parity-0 exchange buffer (8B compiler wt atomics)
  {
    unsigned short h = f2bf(r0);
    unsigned other = __shfl_xor((unsigned)h, 1);
    unsigned vv  = (unsigned)h | (other << 16);        // cols (nn&~1, nn|1)
    unsigned vv2 = __shfl_xor(vv, 2);                  // cols (+2, +3)
    if ((lane & 3) == 0) {
      uint64_t q8 = (uint64_t)vv | ((uint64_t)vv2 << 32);
      __hip_atomic_store((uint64_t*)(ex + (size_t)bg * (N_ / 2) + (nn >> 1)), q8,
                         __ATOMIC_RELAXED, __HIP_MEMORY_SCOPE_AGENT);
    }
  }
  __syncthreads();   // drains vmcnt for all waves -> ex visible before post
  if (tid < BPI)     // wave0 lanes 0..15: one store per consumer block
    __hip_atomic_store(postcol + tid * BPI, 1u,
                       __ATOMIC_RELAXED, __HIP_MEMORY_SCOPE_AGENT);

  // prologue prefetch for t=0 (tail refreshes these for t+1 each step)
  float sn_c = SNp[0], rn_c = RNp[0];
  float4 uc0{}, uc1{};
  if (wave < 2) { const float4* q = (const float4*)Up; uc0 = q[0]; uc1 = q[1]; }

  for (int t = 0; t < T_; ++t) {
    const int par = t & 1;

    // per-wave mailbox poll: lane L checks producer slot L&15 on OUR line
    {
      const unsigned need = (unsigned)(t + 1);
      for (;;) {
        unsigned fv = __hip_atomic_load(myline + l15, __ATOMIC_RELAXED,
                                        __HIP_MEMORY_SCOPE_AGENT);
        if (__all((int)(fv >= need))) break;
        __builtin_amdgcn_s_sleep(1);
      }
    }

    // A fragments: vectorized coherence-point loads. The only YOUNG VMEM
    // here (tail ops from step t-1 are ~1us old, retired under the poll)
    // -> vmcnt(0) == exchange-load RT, nothing else.
    const unsigned* bp = ex + (size_t)par * (B_ * (N_ / 2))
                            + (size_t)abatch * (N_ / 2)
                            + ((wave * KW + koct * 8) >> 1);
    s16x8 afr[KT];
    LDALLS();
    asm volatile("s_waitcnt vmcnt(0)" ::: "memory");
    __builtin_amdgcn_sched_barrier(0);   // rule #18: keep MFMA below the wait

    f32x4 acc[NT];
#pragma unroll
    for (int nt = 0; nt < NT; ++nt) acc[nt] = f32x4{0.f, 0.f, 0.f, 0.f};
#pragma unroll
    for (int kt = 0; kt < KT; ++kt)
#pragma unroll
      for (int nt = 0; nt < NT; ++nt)
        acc[nt] = __builtin_amdgcn_mfma_f32_16x16x32_bf16(afr[kt], bfrag[kt][nt], acc[nt], 0, 0, 0);
    if (wave < 2) {
      s16x8 ua = cvt8(uc0, uc1);
#pragma unroll
      for (int nt = 0; nt < NT; ++nt)
        acc[nt] = __builtin_amdgcn_mfma_f32_16x16x32_bf16(ua, wifrag[nt], acc[nt], 0, 0, 0);
    }

    // cross-wave K-partials; XOR-swizzled slot layout (R4-proven, conflict-0)
    if (lane < 16) {
#pragma unroll
      for (int nt = 0; nt < NT; ++nt) {
        const int s = (nt * 2 + (lane >> 3)) & 3;
        f32x4 a = acc[nt];
        if (s & 1) a = f32x4{a[1], a[0], a[3], a[2]};
        if (s & 2) a = f32x4{a[2], a[3], a[0], a[1]};
        *(f32x4*)&part[wave][nt * 16 + lane][0] = a;   // slot j holds acc[j^s]
      }
    }
    __syncthreads();                                   // B_part
    const int sr = (cc >> 3) & 3;
    const float mat = part[0][cc][bloc ^ sr] + part[1][cc][bloc ^ sr] +
                      part[2][cc][bloc ^ sr] + part[3][cc][bloc ^ sr];
    const float xn = x + 0.1f * (-x + mat + bin + sn_c);
    const float rv = fmaxf(tanhf(xn), 0.f) + rn_c;
    x = xn;

    // publish r_{t+1} (8B compiler wt atomics)
    {
      unsigned short h = f2bf(rv);
      unsigned other = __shfl_xor((unsigned)h, 1);
      unsigned vv  = (unsigned)h | (other << 16);
      unsigned vv2 = __shfl_xor(vv, 2);
      if ((lane & 3) == 0) {
        uint64_t q8 = (uint64_t)vv | ((uint64_t)vv2 << 32);
        __hip_atomic_store((uint64_t*)(ex + (size_t)(par ^ 1) * (B_ * (N_ / 2)) +
                                       (size_t)bg * (N_ / 2) + (nn >> 1)), q8,
                           __ATOMIC_RELAXED, __HIP_MEMORY_SCOPE_AGENT);
      }
    }
    __syncthreads();   // B_drain: all waves' ex stores drained, then post
    if (tid < BPI)     // 16 mailbox stores to 16 consumer-private lines
      __hip_atomic_store(postcol + tid * BPI, (unsigned)(t + 2),
                         __ATOMIC_RELAXED, __HIP_MEMORY_SCOPE_AGENT);

    // ---- TAIL: all auxiliary VMEM, strictly after the post ----
    // X/R stores (current step) + SN/RN/U prefetch for t+1: their acks
    // retire under the next poll, never on the LDALLS drain.
    Xp[(size_t)t * N_] = xn;
    Rp[(size_t)t * N_] = rv;
    if (t + 1 < T_) {
      sn_c = SNp[(size_t)(t + 1) * N_];
      rn_c = RNp[(size_t)(t + 1) * N_];
      if (wave < 2) {
        const float4* q = (const float4*)(Up + (size_t)(t + 1) * NIN_);
        uc0 = q[0]; uc1 = q[1];
      }
    }
  }
}

// ---------------------------------------------------------------------------
// Z = R @ W_out^T + b_out + output_noise.  W_out register-resident; R rows
// double-buffered in LDS; one barrier per row; 512 blocks (R6/R7/R11-proven).
// ---------------------------------------------------------------------------
#define TCH 64
__global__ __launch_bounds__(256, 2) void rnn_zout(
    const float* __restrict__ Rm, const float* __restrict__ ON,
    const float* __restrict__ Wo, const float* __restrict__ Bo,
    float* __restrict__ Z)
{
  const int bid = blockIdx.x;
  const int b = bid >> 3, tq = bid & 7;
  const int tid = threadIdx.x;
  const int o = tid & 31, kc = tid >> 5;

  float4 wv[32];
  const float4* wp = (const float4*)(Wo + (size_t)o * N_ + kc * 128);
#pragma unroll
  for (int i = 0; i < 32; ++i) wv[i] = wp[i];
  const float bo = Bo[o];

  __shared__ float Rl[2][N_];
  __shared__ float zred[2][8][32];

  const int t0 = tq * TCH;
  ((float4*)Rl[0])[tid] = ((const float4*)(Rm + ((size_t)b * T_ + t0) * N_))[tid];
  __syncthreads();

  for (int i = 0; i < TCH; ++i) {
    const int cur = i & 1;
    const size_t row = (size_t)b * T_ + t0 + i;
    float4 nx;
    if (i + 1 < TCH)
      nx = ((const float4*)(Rm + (row + 1) * N_))[tid];
    float a0 = 0.f;
#pragma unroll
    for (int j = 0; j < 32; ++j) {
      const float* rp = &Rl[cur][kc * 128 + j * 4];
      a0 += wv[j].x * rp[0] + wv[j].y * rp[1] + wv[j].z * rp[2] + wv[j].w * rp[3];
    }
    if (i + 1 < TCH)
      ((float4*)Rl[cur ^ 1])[tid] = nx;
    zred[cur][kc][o] = a0;
    __syncthreads();
    if (tid < 32) {
      float z = bo;
#pragma unroll
      for (int k = 0; k < 8; ++k) z += zred[cur][k][tid];
      Z[row * NOUT_ + tid] = z + ON[row * NOUT_ + tid];
    }
    // reduce(i) reads zred[cur] after barrier(i); the next write to the same
    // zred/Rl buffer happens only after barrier(i+1) gates it. Race-free.
  }
}

extern "C" void kernel_launch(void* const* d_in, const int* in_sizes, int n_in,
                              void* d_out, int out_size, void* d_ws, size_t ws_size,
                              hipStream_t stream) {
  const float* U  = (const float*)d_in[0];
  const float* X0 = (const float*)d_in[1];
  const float* SN = (const float*)d_in[2];
  const float* RN = (const float*)d_in[3];
  const float* ON = (const float*)d_in[4];
  const float* Wi = (const float*)d_in[5];
  const float* Bi = (const float*)d_in[6];
  const float* Wr = (const float*)d_in[7];
  const float* Wo = (const float*)d_in[8];
  const float* Bo = (const float*)d_in[9];

  float* X = (float*)d_out;
  float* R = X + (size_t)B_ * T_ * N_;
  float* Z = R + (size_t)B_ * T_ * N_;

  unsigned* mail = (unsigned*)d_ws;                        // [NISL][16][16]
  unsigned* ex   = (unsigned*)((char*)d_ws + 65536);       // [2][B_][N_/2] bf16x2

  // zero mailboxes every call (graph-capture-safe; 0 < first need of 1)
  hipMemsetAsync(mail, 0, MAIL_WORDS * sizeof(unsigned), stream);

  hipLaunchKernelGGL(rnn_scan, dim3(NISL * BPI), dim3(256), 0, stream,
                     U, X0, SN, RN, Wi, Bi, Wr, X, R, mail, ex);
  hipLaunchKernelGGL(rnn_zout, dim3(B_ * (T_ / TCH)), dim3(256), 0, stream,
                     R, ON, Wo, Bo, Z);
}